// Round 8
// baseline (57.847 us; speedup 1.0000x reference)
//
#include <hip/hip_runtime.h>

#define TT 16384
#define DD 2048
#define EE 64
#define NBLK 512

typedef __attribute__((ext_vector_type(8))) short bf16x8;
typedef __attribute__((ext_vector_type(8))) unsigned short ushort8;
typedef __attribute__((ext_vector_type(4))) float f32x4;
typedef __attribute__((ext_vector_type(16))) float f32x16;

__device__ __forceinline__ unsigned short bf16_rne(float f) {
    unsigned u = __float_as_uint(f);
    return (unsigned short)((u + 0x7FFFu + ((u >> 16) & 1u)) >> 16);
}
__device__ __forceinline__ float bf16_f32(unsigned short h) {
    return __uint_as_float(((unsigned)h) << 16);
}
__device__ __forceinline__ unsigned cvt_pk(float lo, float hi) {
    unsigned r;
    asm("v_cvt_pk_bf16_f32 %0, %1, %2" : "=v"(r) : "v"(lo), "v"(hi));
    return r;  // low16 = bf16(lo), high16 = bf16(hi)
}
__device__ __forceinline__ bf16x8 pack4(unsigned a, unsigned b, unsigned c, unsigned d) {
    union { unsigned u[4]; bf16x8 v; } t;
    t.u[0] = a; t.u[1] = b; t.u[2] = c; t.u[3] = d;
    return t.v;
}

// ---------------------------------------------------------------------------
// W [2048][64] f32 -> wpack: 32x32x16 A-fragments per 16-k chunk t=0..127.
// frag_id = t*4 + m*2 + h ; wpack[frag_id*512 + lane*8 + j] = bf16(hi/lo) of
//   wg[(t*16 + (lane>>5)*8 + j)*64 + m*32 + (lane&31)]
// Block 0 additionally zeros the global bins + completion counter.
__global__ __launch_bounds__(256)
void wconv(const float* __restrict__ wg, unsigned short* __restrict__ wpack,
           float* __restrict__ gbins, unsigned* __restrict__ cnt) {
    if (blockIdx.x == 0) {
        if (threadIdx.x < 64) gbins[threadIdx.x] = 0.0f;
        if (threadIdx.x == 64) *cnt = 0u;
    }
    const int g = (int)blockIdx.x * 256 + threadIdx.x;  // 32768 threads
    const int t = g >> 8, m = (g >> 7) & 1, h = (g >> 6) & 1, lane = g & 63;
    const int e = m * 32 + (lane & 31);
    const int ks = t * 16 + (lane >> 5) * 8;
    ushort8 v;
#pragma unroll
    for (int j = 0; j < 8; ++j) {
        const float f = wg[(size_t)(ks + j) * EE + e];
        const unsigned short hi = bf16_rne(f);
        v[j] = h ? bf16_rne(f - bf16_f32(hi)) : hi;
    }
    *(ushort8*)(wpack + (size_t)g * 8) = v;
}

// ---------------------------------------------------------------------------
// Fused gate GEMM (32x32x16 bf16x3, register-only datapath) + biased top-2 +
// softmax + global bins + last-block EMA.  512 thr = 8 waves on the same 32
// tokens; wave q owns K-eighth [q*256,+256), 16 steps x 16 k.  x B-frags are
// 32 contiguous bytes/lane loaded straight to VGPRs, named 3-deep pipeline;
// W A-frags from wpack (L2-hot, 1 KB/instr coalesced), named 2-deep.  No LDS
// in the K-loop; LDS only for the 8-way K reduce.  Grid 512 = 2 blocks/CU.
__global__ __launch_bounds__(512, 4)
void gate_fused(const float* __restrict__ x, const unsigned short* __restrict__ wpack,
                const float* __restrict__ loads, float* __restrict__ out,
                float* __restrict__ gbins, unsigned* __restrict__ cnt) {
    __shared__ __align__(16) float arena[7 * 64 * 36];  // 63 KB reduce overlay
    __shared__ float bins[64];

    const int tid = threadIdx.x, lane = tid & 63, q = tid >> 6;
    const int tb = (int)blockIdx.x;
    const int tok = lane & 31, hi5 = lane >> 5;

    f32x16 acc[2];
#pragma unroll
    for (int m = 0; m < 2; ++m)
#pragma unroll
        for (int r = 0; r < 16; ++r) acc[m][r] = 0.0f;

    const float* xr = x + (size_t)(tb * 32 + tok) * DD + q * 256 + hi5 * 8;
    const unsigned short* wq = wpack + (size_t)(q * 16) * 2048 + lane * 8;

    auto loadW = [&](int s, bf16x8 (&Wr)[4]) {
        const unsigned short* b = wq + (size_t)s * 2048;
#pragma unroll
        for (int f = 0; f < 4; ++f)
            Wr[f] = *(const bf16x8*)(b + (size_t)f * 512);
    };
    auto loadX = [&](int s, f32x4& xa, f32x4& xb) {
        xa = *(const f32x4*)(xr + s * 16);
        xb = *(const f32x4*)(xr + s * 16 + 4);
    };
    auto compute = [&](const f32x4& xa, const f32x4& xb, bf16x8 (&Wr)[4]) {
        const float cf[8] = {xa.x, xa.y, xa.z, xa.w, xb.x, xb.y, xb.z, xb.w};
        unsigned ph[4], pl[4];
#pragma unroll
        for (int j = 0; j < 4; ++j) {
            ph[j] = cvt_pk(cf[2 * j], cf[2 * j + 1]);
            const float h0 = __uint_as_float(ph[j] << 16);
            const float h1 = __uint_as_float(ph[j] & 0xFFFF0000u);
            pl[j] = cvt_pk(cf[2 * j] - h0, cf[2 * j + 1] - h1);
        }
        const bf16x8 bhi = pack4(ph[0], ph[1], ph[2], ph[3]);
        const bf16x8 blo = pack4(pl[0], pl[1], pl[2], pl[3]);
#pragma unroll
        for (int m = 0; m < 2; ++m) {
            acc[m] = __builtin_amdgcn_mfma_f32_32x32x16_bf16(Wr[m * 2], bhi, acc[m], 0, 0, 0);
            acc[m] = __builtin_amdgcn_mfma_f32_32x32x16_bf16(Wr[m * 2], blo, acc[m], 0, 0, 0);
            acc[m] = __builtin_amdgcn_mfma_f32_32x32x16_bf16(Wr[m * 2 + 1], bhi, acc[m], 0, 0, 0);
        }
    };

    f32x4 xa0, xb0, xa1, xb1, xa2, xb2;
    bf16x8 WA[4], WB[4];

    // prologue: x 3-deep, W for step 0
    loadX(0, xa0, xb0);
    loadX(1, xa1, xb1);
    loadX(2, xa2, xb2);
    loadW(0, WA);

    // STEP(s, slot, Wuse, Wload): issue W(s+1), compute s, refill slot with s+3
#define STEP(s, sl, WU, WL)                          \
    do {                                             \
        if ((s) < 15) loadW((s) + 1, W##WL);         \
        compute(xa##sl, xb##sl, W##WU);              \
        if ((s) + 3 < 16) loadX((s) + 3, xa##sl, xb##sl); \
    } while (0)

    STEP(0, 0, A, B);  STEP(1, 1, B, A);  STEP(2, 2, A, B);  STEP(3, 0, B, A);
    STEP(4, 1, A, B);  STEP(5, 2, B, A);  STEP(6, 0, A, B);  STEP(7, 1, B, A);
    STEP(8, 2, A, B);  STEP(9, 0, B, A);  STEP(10, 1, A, B); STEP(11, 2, B, A);
    STEP(12, 0, A, B); STEP(13, 1, B, A); STEP(14, 2, A, B); STEP(15, 0, B, A);
#undef STEP

    // ---- deterministic 8-way K-split reduce through LDS ------------------
    if (q != 0) {
        float* ov = arena + (size_t)(q - 1) * 2304 + lane * 36;
#pragma unroll
        for (int m = 0; m < 2; ++m)
#pragma unroll
            for (int p = 0; p < 4; ++p) {
                const f32x4 t_ = {acc[m][p * 4], acc[m][p * 4 + 1],
                                  acc[m][p * 4 + 2], acc[m][p * 4 + 3]};
                *(f32x4*)(ov + m * 16 + p * 4) = t_;
            }
    }
    __syncthreads();
    if (q != 0) return;

#pragma unroll 1
    for (int qq = 0; qq < 7; ++qq) {
        const float* ov = arena + (size_t)qq * 2304 + lane * 36;
#pragma unroll
        for (int m = 0; m < 2; ++m)
#pragma unroll
            for (int p = 0; p < 4; ++p) {
                const f32x4 t_ = *(const f32x4*)(ov + m * 16 + p * 4);
#pragma unroll
                for (int j = 0; j < 4; ++j) acc[m][p * 4 + j] += t_[j];
            }
    }

    // ---- top-2 (biased): lane holds e = m*32 + (r&3) + 8*(r>>2) + 4*hi5 --
    float v1 = -3.4e38f, u1 = 0.0f, v2 = -3.4e38f, u2 = 0.0f;
    int i1 = 0x7fffffff, i2 = 0x7fffffff;
#pragma unroll
    for (int m = 0; m < 2; ++m)
#pragma unroll
        for (int r = 0; r < 16; ++r) {
            const int e = m * 32 + (r & 3) + 8 * (r >> 2) + 4 * hi5;
            const float u = acc[m][r];
            const float b = u - (loads[e] - 0.015625f) * 2.0f;
            if ((b > v1) || (b == v1 && e < i1)) {
                v2 = v1; u2 = u1; i2 = i1;
                v1 = b;  u1 = u;  i1 = e;
            } else if ((b > v2) || (b == v2 && e < i2)) {
                v2 = b; u2 = u; i2 = e;
            }
        }
    {   // merge lane <-> lane+32 (same token, other expert rows)
        const float ov1 = __shfl_xor(v1, 32), ou1 = __shfl_xor(u1, 32);
        const float ov2 = __shfl_xor(v2, 32), ou2 = __shfl_xor(u2, 32);
        const int oi1 = __shfl_xor(i1, 32), oi2 = __shfl_xor(i2, 32);
        if ((ov1 > v1) || (ov1 == v1 && oi1 < i1)) {
            if ((v1 > ov2) || (v1 == ov2 && i1 < oi2)) { v2 = v1; u2 = u1; i2 = i1; }
            else                                        { v2 = ov2; u2 = ou2; i2 = oi2; }
            v1 = ov1; u1 = ou1; i1 = oi1;
        } else if ((ov1 > v2) || (ov1 == v2 && oi1 < i2)) {
            v2 = ov1; u2 = ou1; i2 = oi1;
        }
    }

    bins[lane] = 0.0f;
    if (lane < 32) {
        const int tg = tb * 32 + tok;
        const float mx = fmaxf(u1, u2);
        const float e1 = __expf(u1 - mx), e2 = __expf(u2 - mx);
        const float w1 = e1 / (e1 + e2), w2 = e2 / (e1 + e2);
        *(float2*)(out + 2 * tg) = make_float2(w1, w2);
        *(float2*)(out + 2 * TT + 2 * tg) = make_float2((float)i1, (float)i2);
        atomicAdd(&bins[i1], w1);
        atomicAdd(&bins[i2], w2);
    }
    // wave 0 only from here: publish block bins, last block does the EMA.
    atomicAdd(&gbins[lane], bins[lane]);
    __threadfence();
    unsigned old = 0;
    if (lane == 0) old = atomicAdd(cnt, 1u);
    old = __shfl((int)old, 0);
    if (old == NBLK - 1) {
        __threadfence();
        const float tot = atomicAdd(&gbins[lane], 0.0f);  // coherent read
        out[4 * TT + lane] = 0.9f * loads[lane] + 0.1f * (tot * (1.0f / 16384.0f));
    }
}

// ---------------------------------------------------------------------------
extern "C" void kernel_launch(void* const* d_in, const int* in_sizes, int n_in,
                              void* d_out, int out_size, void* d_ws, size_t ws_size,
                              hipStream_t stream) {
    const float* x = (const float*)d_in[0];      // [16384, 2048]
    const float* wg = (const float*)d_in[1];     // [2048, 64]
    const float* loads = (const float*)d_in[2];  // [64]
    float* out = (float*)d_out;

    unsigned short* wpack = (unsigned short*)d_ws;             // 512 KB
    float* gbins = (float*)(wpack + (size_t)128 * 4 * 512);    // [64]
    unsigned* cnt = (unsigned*)(gbins + 64);                   // [1]

    hipLaunchKernelGGL(wconv, dim3(128), dim3(256), 0, stream, wg, wpack, gbins, cnt);
    hipLaunchKernelGGL(gate_fused, dim3(NBLK), dim3(512), 0, stream,
                       x, wpack, loads, out, gbins, cnt);
}